// Round 3
// baseline (1718.152 us; speedup 1.0000x reference)
//
#include <hip/hip_runtime.h>

#define T_ 768
#define A_ 24
#define S_ 576
#define Q_ 32
#define K_ 128
#define CA_ 128
#define CP_ 16

typedef const float* fp;

// pre-scaled pair-LN weights: wv[c][j] = ln_p[c]*w_tp[c][j]; cw[j] = sum_c wv[c][j]
__device__ float g_wv[2048];
__device__ float g_cw[16];

// ---------------- kernel 1: token_atoms_single_cond (T*A blocks, 128 thr) ----
__global__ void k_token_atoms(fp ref_ops, fp ref_mask, const int* ref_element,
                              fp ref_charge, const int* name_chars,
                              fp w_pos, fp w_maskw, fp w_elem, fp w_chg, fp w_name,
                              float* ws_tok)
{
    int ta = blockIdx.x;
    int c  = threadIdx.x;
    float p0 = ref_ops[ta*3+0];
    float p1 = ref_ops[ta*3+1];
    float p2 = ref_ops[ta*3+2];
    float m  = ref_mask[ta];
    int   e  = ref_element[ta];
    float chg= asinhf(ref_charge[ta]);
    float acc = p0*w_pos[0*CA_+c] + p1*w_pos[1*CA_+c] + p2*w_pos[2*CA_+c];
    acc += m * w_maskw[c];
    acc += w_elem[e*CA_+c];
    acc += chg * w_chg[c];
    #pragma unroll
    for (int j=0;j<4;j++){
        int v = name_chars[ta*4+j];
        acc += w_name[(j*64+v)*CA_+c];
    }
    ws_tok[ta*CA_+c] = acc * m;
}

// ---------------- kernel 2: tsc = LN(trunk_single) @ w_ts (T blocks, 128 thr)
__global__ void k_tsc(fp trunk_single, fp ln_s_scale, fp w_ts, float* ws_tsc)
{
    int t = blockIdx.x; int c = threadIdx.x;
    __shared__ float xh[384];
    __shared__ float red[128];
    float x0 = trunk_single[t*384 + c];
    float x1 = trunk_single[t*384 + 128 + c];
    float x2 = trunk_single[t*384 + 256 + c];
    red[c] = x0+x1+x2; __syncthreads();
    for (int off=64; off>0; off>>=1){ if (c<off) red[c]+=red[c+off]; __syncthreads(); }
    float mu = red[0] / 384.f;
    __syncthreads();
    float d0=x0-mu, d1=x1-mu, d2=x2-mu;
    red[c] = d0*d0+d1*d1+d2*d2; __syncthreads();
    for (int off=64; off>0; off>>=1){ if (c<off) red[c]+=red[c+off]; __syncthreads(); }
    float rs = rsqrtf(red[0]/384.f + 1e-5f);
    __syncthreads();
    xh[c]     = d0*rs*ln_s_scale[c];
    xh[c+128] = d1*rs*ln_s_scale[c+128];
    xh[c+256] = d2*rs*ln_s_scale[c+256];
    __syncthreads();
    float acc=0.f;
    for (int i=0;i<384;i++) acc += xh[i]*w_ts[i*CA_+c];
    ws_tsc[t*CA_+c]=acc;
}

// ---------------- kernel 3: queries_single_cond + row_act (S*Q blocks) -------
__global__ void k_queries(const float* ws_tok, const float* ws_tsc,
                          const int* a2q_idx, const int* a2q_mask,
                          const int* t2q_idx, const int* t2q_mask,
                          fp w_row,
                          float* ws_q, float* ws_rowa, float* out_q)
{
    int i = blockIdx.x; int c = threadIdx.x;
    __shared__ float r[128];
    __shared__ float part[128];
    float v = 0.f;
    if (a2q_mask[i]) v += ws_tok[a2q_idx[i]*CA_ + c];
    if (t2q_mask[i]) v += ws_tsc[t2q_idx[i]*CA_ + c];
    ws_q[i*CA_+c] = v;
    out_q[i*CA_+c] = v;
    r[c] = fmaxf(v, 0.f);
    __syncthreads();
    int j = c & 15, ch = c >> 4;
    float acc = 0.f;
    #pragma unroll
    for (int ii=0; ii<16; ii++) acc += r[ch*16+ii]*w_row[(ch*16+ii)*16+j];
    part[c] = acc; __syncthreads();
    if (c < 16){
        float a2 = 0.f;
        #pragma unroll
        for (int ch2=0; ch2<8; ch2++) a2 += part[ch2*16+c];
        ws_rowa[i*16+c] = a2;
    }
}

// ---------------- kernel 4: keys_single_cond + keys_mask + col_act (S*K) -----
__global__ void k_keys(const float* ws_q, const int* q2k_idx, const int* q2k_mask,
                       const int* queries_mask, fp w_col,
                       float* ws_cola, float* out_keys, float* out_kmask)
{
    int i = blockIdx.x; int c = threadIdx.x;
    __shared__ float r[128];
    __shared__ float part[128];
    int gi = q2k_idx[i]; int m = q2k_mask[i];
    float v = m ? ws_q[gi*CA_+c] : 0.f;
    out_keys[i*CA_+c] = v;
    if (c==0) out_kmask[i] = (m && queries_mask[gi]) ? 1.f : 0.f;
    r[c] = fmaxf(v, 0.f);
    __syncthreads();
    int j = c & 15, ch = c >> 4;
    float acc = 0.f;
    #pragma unroll
    for (int ii=0; ii<16; ii++) acc += r[ch*16+ii]*w_col[(ch*16+ii)*16+j];
    part[c] = acc; __syncthreads();
    if (c < 16){
        float a2 = 0.f;
        #pragma unroll
        for (int ch2=0; ch2<8; ch2++) a2 += part[ch2*16+c];
        ws_cola[i*16+c] = a2;
    }
}

// ---------------- kernel 5a: fold ln_p_scale into w_tp, compute col sums -----
__global__ void k_tpc_prep(fp w_tp, fp ln_p_scale)
{
    int i = threadIdx.x;  // 256
    for (int r = i; r < 2048; r += 256) g_wv[r] = w_tp[r] * ln_p_scale[r >> 4];
    __syncthreads();
    if (i < 16){
        float s = 0.f;
        #pragma unroll
        for (int c = 0; c < 128; c++) s += g_wv[c*16 + i];
        g_cw[i] = s;
    }
}

// ---------------- kernel 5b: tpc — LDS-staged coalesced, one thread per row --
// tpc[pid][j] = rs * ( dot(x, wv[:,j]) - mu*cw[j] ),  mu/rs from raw x moments.
// 256 rows/block; the 32 f4-columns are processed in 4 chunks of 8 f4, double-
// buffered (2 x 32 KB = 64 KB -> 2 blocks/CU). Staging is coalesced f4 loads;
// XOR-swizzle c4^= (r&7) inside each 128 B group makes both ds_write_b128 and
// the per-row ds_read_b128 cover all 32 banks (conflict-free b128).
// Weights stay wave-uniform -> s_load / K$ (zero vector-memory cost).
__global__ __launch_bounds__(256) void k_tpc2(fp trunk_pair, float* ws_tpc)
{
    __shared__ float4 tile[2][256*8];
    int t = threadIdx.x;
    const float4* src = (const float4*)trunk_pair + (size_t)blockIdx.x * (256*32);

    // stage chunk 0 into buf 0
    #pragma unroll
    for (int p=0;p<8;p++){
        int li = p*256 + t;
        int r = li>>3, c4 = li&7;
        tile[0][r*8 + (c4 ^ (r&7))] = src[r*32 + c4];
    }

    float pj[16];
    #pragma unroll
    for (int j=0;j<16;j++) pj[j]=0.f;
    float s1=0.f, s2=0.f;
    int r7 = t & 7;

    #pragma unroll
    for (int ch=0; ch<4; ch++){
        __syncthreads();
        if (ch < 3){
            int nb = (ch+1)&1;
            #pragma unroll
            for (int p=0;p<8;p++){
                int li = p*256 + t;
                int r = li>>3, c4 = li&7;
                tile[nb][r*8 + (c4 ^ (r&7))] = src[r*32 + (ch+1)*8 + c4];
            }
        }
        int cb = ch&1;
        #pragma unroll
        for (int c4=0;c4<8;c4++){
            float4 x = tile[cb][t*8 + (c4 ^ r7)];
            s1 += (x.x+x.y)+(x.z+x.w);
            s2 += x.x*x.x + x.y*x.y + x.z*x.z + x.w*x.w;
            const float* w0 = g_wv + (ch*8+c4)*64;   // uniform -> s_load
            #pragma unroll
            for (int j=0;j<16;j++)
                pj[j] += x.x*w0[j] + x.y*w0[16+j] + x.z*w0[32+j] + x.w*w0[48+j];
        }
    }

    float mu  = s1*(1.f/128.f);
    float var = s2*(1.f/128.f) - mu*mu;
    float rs  = rsqrtf(var + 1e-5f);
    size_t pid = (size_t)blockIdx.x*256 + t;
    float4* dst = (float4*)(ws_tpc + pid*16);
    #pragma unroll
    for (int j4=0;j4<4;j4++){
        float4 o;
        o.x = rs*(pj[j4*4+0] - mu*g_cw[j4*4+0]);
        o.y = rs*(pj[j4*4+1] - mu*g_cw[j4*4+1]);
        o.z = rs*(pj[j4*4+2] - mu*g_cw[j4*4+2]);
        o.w = rs*(pj[j4*4+3] - mu*g_cw[j4*4+3]);
        dst[j4]=o;
    }
}

// ---------------- kernel 6a/6b: geometry gathers -----------------------------
__global__ void k_qgeo(fp ref_ops, const int* ref_uid, const int* a2q_idx, const int* a2q_mask,
                       float* qpos, int* quid)
{
    int i = blockIdx.x*256 + threadIdx.x;
    if (i >= S_*Q_) return;
    int gi = a2q_idx[i]; int m = a2q_mask[i];
    qpos[i*3+0] = m ? ref_ops[gi*3+0] : 0.f;
    qpos[i*3+1] = m ? ref_ops[gi*3+1] : 0.f;
    qpos[i*3+2] = m ? ref_ops[gi*3+2] : 0.f;
    quid[i] = m ? ref_uid[gi] : 0;
}

__global__ void k_kgeo(const float* qpos, const int* ref_uid, const int* q2k_idx, const int* q2k_mask,
                       float* kpos, int* kuid)
{
    int i = blockIdx.x*256 + threadIdx.x;
    if (i >= S_*K_) return;
    int gi = q2k_idx[i]; int m = q2k_mask[i];
    kpos[i*3+0] = m ? qpos[gi*3+0] : 0.f;
    kpos[i*3+1] = m ? qpos[gi*3+1] : 0.f;
    kpos[i*3+2] = m ? qpos[gi*3+2] : 0.f;
    kuid[i] = m ? ref_uid[gi] : 0;   // NB: raw ref_space_uid flat, per reference
}

// ---------------- kernel 7: pair_act — 2 k-elems/thread, weights via s_load --
__global__ __launch_bounds__(256) void k_pair2(
    const float* ws_rowa, const float* ws_cola, const float* ws_tpc,
    const float* qpos, const float* kpos, const int* quid, const int* kuid,
    const int* t2q_idx, const int* t2q_mask, const int* t2k_idx, const int* t2k_mask,
    fp w_off, fp w_dist, fp w_valid, fp w_m1, fp w_m2, fp w_m3,
    float* out_pair)
{
    int tid = threadIdx.x;
    int sq  = blockIdx.x*4 + (tid>>6);      // wave-uniform
    int k0  = (tid&63)*2;
    int s   = sq >> 5;
    int sk0 = s*K_ + k0;

    float p0[16], p1[16];
    const float4* ra = (const float4*)(ws_rowa + (size_t)sq*16);
    const float4* ca = (const float4*)(ws_cola + (size_t)sk0*16);
    #pragma unroll
    for (int j4=0;j4<4;j4++){
        float4 a  = ra[j4];
        float4 b0 = ca[j4];
        float4 b1 = ca[4+j4];
        p0[j4*4+0]=a.x+b0.x; p0[j4*4+1]=a.y+b0.y; p0[j4*4+2]=a.z+b0.z; p0[j4*4+3]=a.w+b0.w;
        p1[j4*4+0]=a.x+b1.x; p1[j4*4+1]=a.y+b1.y; p1[j4*4+2]=a.z+b1.z; p1[j4*4+3]=a.w+b1.w;
    }

    int tqm = t2q_mask[sq];
    int tq  = t2q_idx[sq];
    int2 km = *(const int2*)(t2k_mask + sk0);
    int2 kv = *(const int2*)(t2k_idx + sk0);
    if (tqm && km.x){
        const float4* tp = (const float4*)(ws_tpc + (size_t)(tq*T_ + kv.x)*16);
        #pragma unroll
        for (int j4=0;j4<4;j4++){
            float4 v = tp[j4];
            p0[j4*4+0]+=v.x; p0[j4*4+1]+=v.y; p0[j4*4+2]+=v.z; p0[j4*4+3]+=v.w;
        }
    }
    if (tqm && km.y){
        const float4* tp = (const float4*)(ws_tpc + (size_t)(tq*T_ + kv.y)*16);
        #pragma unroll
        for (int j4=0;j4<4;j4++){
            float4 v = tp[j4];
            p1[j4*4+0]+=v.x; p1[j4*4+1]+=v.y; p1[j4*4+2]+=v.z; p1[j4*4+3]+=v.w;
        }
    }

    float qx=qpos[sq*3+0], qy=qpos[sq*3+1], qz=qpos[sq*3+2];
    int   qu=quid[sq];
    const float2* kp = (const float2*)(kpos + (size_t)sk0*3);  // 6 floats, 8B-aligned
    float2 ka=kp[0], kb=kp[1], kc=kp[2];
    int2 ku = *(const int2*)(kuid + sk0);
    {
        float ox=qx-ka.x, oy=qy-ka.y, oz=qz-kb.x;
        float val = (qu==ku.x) ? 1.f : 0.f;
        float invd = val/(1.f + ox*ox+oy*oy+oz*oz);
        ox*=val; oy*=val; oz*=val;
        #pragma unroll
        for (int j=0;j<16;j++)
            p0[j] += ox*w_off[j] + oy*w_off[16+j] + oz*w_off[32+j]
                   + invd*w_dist[j] + val*w_valid[j];
    }
    {
        float ox=qx-kb.y, oy=qy-kc.x, oz=qz-kc.y;
        float val = (qu==ku.y) ? 1.f : 0.f;
        float invd = val/(1.f + ox*ox+oy*oy+oz*oz);
        ox*=val; oy*=val; oz*=val;
        #pragma unroll
        for (int j=0;j<16;j++)
            p1[j] += ox*w_off[j] + oy*w_off[16+j] + oz*w_off[32+j]
                   + invd*w_dist[j] + val*w_valid[j];
    }

    // MLP: p += relu(relu(relu(p)@m1)@m2)@m3   (all static indexing)
    float h0[16], h1[16];
    #pragma unroll
    for (int j=0;j<16;j++){ h0[j]=0.f; h1[j]=0.f; }
    #pragma unroll
    for (int i=0;i<16;i++){
        float r0=fmaxf(p0[i],0.f), r1=fmaxf(p1[i],0.f);
        #pragma unroll
        for (int j=0;j<16;j++){ float w=w_m1[i*16+j]; h0[j]+=r0*w; h1[j]+=r1*w; }
    }
    float g0[16], g1[16];
    #pragma unroll
    for (int j=0;j<16;j++){ g0[j]=0.f; g1[j]=0.f; }
    #pragma unroll
    for (int i=0;i<16;i++){
        float r0=fmaxf(h0[i],0.f), r1=fmaxf(h1[i],0.f);
        #pragma unroll
        for (int j=0;j<16;j++){ float w=w_m2[i*16+j]; g0[j]+=r0*w; g1[j]+=r1*w; }
    }
    #pragma unroll
    for (int i=0;i<16;i++){
        float r0=fmaxf(g0[i],0.f), r1=fmaxf(g1[i],0.f);
        #pragma unroll
        for (int j=0;j<16;j++){ float w=w_m3[i*16+j]; p0[j]+=r0*w; p1[j]+=r1*w; }
    }

    float4* dst = (float4*)(out_pair + ((size_t)sq*K_ + k0)*16);
    #pragma unroll
    for (int j4=0;j4<4;j4++){
        float4 v0; v0.x=p0[j4*4+0]; v0.y=p0[j4*4+1]; v0.z=p0[j4*4+2]; v0.w=p0[j4*4+3];
        float4 v1; v1.x=p1[j4*4+0]; v1.y=p1[j4*4+1]; v1.z=p1[j4*4+2]; v1.w=p1[j4*4+3];
        dst[j4]   = v0;
        dst[4+j4] = v1;
    }
}

// ---------------- launch -----------------------------------------------------
extern "C" void kernel_launch(void* const* d_in, const int* in_sizes, int n_in,
                              void* d_out, int out_size, void* d_ws, size_t ws_size,
                              hipStream_t stream)
{
    fp trunk_single = (fp)d_in[0];
    fp trunk_pair   = (fp)d_in[1];
    fp ref_ops      = (fp)d_in[2];
    fp ref_mask     = (fp)d_in[3];
    const int* ref_element  = (const int*)d_in[4];
    fp ref_charge   = (fp)d_in[5];
    const int* name_chars   = (const int*)d_in[6];
    const int* ref_uid      = (const int*)d_in[7];
    const int* queries_mask = (const int*)d_in[8];
    const int* a2q_idx = (const int*)d_in[9];
    const int* a2q_mask= (const int*)d_in[10];
    const int* q2k_idx = (const int*)d_in[11];
    const int* q2k_mask= (const int*)d_in[12];
    const int* t2q_idx = (const int*)d_in[13];
    const int* t2q_mask= (const int*)d_in[14];
    const int* t2k_idx = (const int*)d_in[15];
    const int* t2k_mask= (const int*)d_in[16];
    fp w_pos  = (fp)d_in[17];
    fp w_maskw= (fp)d_in[18];
    fp w_elem = (fp)d_in[19];
    fp w_chg  = (fp)d_in[20];
    fp w_name = (fp)d_in[21];
    fp ln_s   = (fp)d_in[22];
    fp w_ts   = (fp)d_in[23];
    fp w_row  = (fp)d_in[24];
    fp w_col  = (fp)d_in[25];
    fp ln_p   = (fp)d_in[26];
    fp w_tp   = (fp)d_in[27];
    fp w_off  = (fp)d_in[28];
    fp w_dist = (fp)d_in[29];
    fp w_valid= (fp)d_in[30];
    fp w_m1   = (fp)d_in[31];
    fp w_m2   = (fp)d_in[32];
    fp w_m3   = (fp)d_in[33];

    float* out = (float*)d_out;
    float* out_q     = out;                                   // 2,359,296
    float* out_pair  = out + 2359296;                         // 37,748,736
    float* out_kmask = out + 2359296 + 37748736;              // 73,728
    float* out_keys  = out + 2359296 + 37748736 + 73728;      // 9,437,184

    float* ws = (float*)d_ws;                 // same layout as previous version
    float* ws_tok = ws;                       // T*A*CA    = 2,359,296
    float* ws_tsc = ws_tok + 2359296;         // T*CA      = 98,304
    float* ws_q   = ws_tsc + 98304;           // S*Q*CA    = 2,359,296
    float* ws_rowa= ws_q   + 2359296;         // S*Q*16    = 294,912
    float* ws_cola= ws_rowa+ 294912;          // S*K*16    = 1,179,648
    float* ws_tpc = ws_cola+ 1179648;         // T*T*16    = 9,437,184
    float* ws_qpos= ws_tpc + 9437184;         // S*Q*3     = 55,296
    float* ws_kpos= ws_qpos+ 55296;           // S*K*3     = 221,184
    int*   ws_quid= (int*)(ws_kpos + 221184); // S*Q       = 18,432
    int*   ws_kuid= ws_quid + 18432;          // S*K       = 73,728

    k_token_atoms<<<T_*A_, 128, 0, stream>>>(ref_ops, ref_mask, ref_element, ref_charge,
        name_chars, w_pos, w_maskw, w_elem, w_chg, w_name, ws_tok);
    k_tsc<<<T_, 128, 0, stream>>>(trunk_single, ln_s, w_ts, ws_tsc);
    k_queries<<<S_*Q_, 128, 0, stream>>>(ws_tok, ws_tsc, a2q_idx, a2q_mask, t2q_idx, t2q_mask,
        w_row, ws_q, ws_rowa, out_q);
    k_keys<<<S_*K_, 128, 0, stream>>>(ws_q, q2k_idx, q2k_mask, queries_mask, w_col,
        ws_cola, out_keys, out_kmask);
    k_tpc_prep<<<1, 256, 0, stream>>>(w_tp, ln_p);
    k_tpc2<<<(T_*T_)/256, 256, 0, stream>>>(trunk_pair, ws_tpc);
    k_qgeo<<<(S_*Q_+255)/256, 256, 0, stream>>>(ref_ops, ref_uid, a2q_idx, a2q_mask, ws_qpos, ws_quid);
    k_kgeo<<<(S_*K_+255)/256, 256, 0, stream>>>(ws_qpos, ref_uid, q2k_idx, q2k_mask, ws_kpos, ws_kuid);
    k_pair2<<<(S_*Q_*K_)/512, 256, 0, stream>>>(ws_rowa, ws_cola, ws_tpc, ws_qpos, ws_kpos,
        ws_quid, ws_kuid, t2q_idx, t2q_mask, t2k_idx, t2k_mask,
        w_off, w_dist, w_valid, w_m1, w_m2, w_m3, out_pair);
}

// Round 4
// 847.560 us; speedup vs baseline: 2.0272x; 2.0272x over previous
//
#include <hip/hip_runtime.h>

#define T_ 768
#define A_ 24
#define S_ 576
#define Q_ 32
#define K_ 128
#define CA_ 128
#define CP_ 16

typedef const float* fp;

// pre-scaled pair-LN weights: wv[c][j] = ln_p[c]*w_tp[c][j]; cw[j] = sum_c wv[c][j]
__device__ float g_wv[2048];
__device__ float g_cw[16];

// ---------------- kernel 1: token_atoms_single_cond (T*A blocks, 128 thr) ----
__global__ void k_token_atoms(fp ref_ops, fp ref_mask, const int* ref_element,
                              fp ref_charge, const int* name_chars,
                              fp w_pos, fp w_maskw, fp w_elem, fp w_chg, fp w_name,
                              float* ws_tok)
{
    int ta = blockIdx.x;
    int c  = threadIdx.x;
    float p0 = ref_ops[ta*3+0];
    float p1 = ref_ops[ta*3+1];
    float p2 = ref_ops[ta*3+2];
    float m  = ref_mask[ta];
    int   e  = ref_element[ta];
    float chg= asinhf(ref_charge[ta]);
    float acc = p0*w_pos[0*CA_+c] + p1*w_pos[1*CA_+c] + p2*w_pos[2*CA_+c];
    acc += m * w_maskw[c];
    acc += w_elem[e*CA_+c];
    acc += chg * w_chg[c];
    #pragma unroll
    for (int j=0;j<4;j++){
        int v = name_chars[ta*4+j];
        acc += w_name[(j*64+v)*CA_+c];
    }
    ws_tok[ta*CA_+c] = acc * m;
}

// ---------------- kernel 2: tsc = LN(trunk_single) @ w_ts (T blocks, 128 thr)
__global__ void k_tsc(fp trunk_single, fp ln_s_scale, fp w_ts, float* ws_tsc)
{
    int t = blockIdx.x; int c = threadIdx.x;
    __shared__ float xh[384];
    __shared__ float red[128];
    float x0 = trunk_single[t*384 + c];
    float x1 = trunk_single[t*384 + 128 + c];
    float x2 = trunk_single[t*384 + 256 + c];
    red[c] = x0+x1+x2; __syncthreads();
    for (int off=64; off>0; off>>=1){ if (c<off) red[c]+=red[c+off]; __syncthreads(); }
    float mu = red[0] / 384.f;
    __syncthreads();
    float d0=x0-mu, d1=x1-mu, d2=x2-mu;
    red[c] = d0*d0+d1*d1+d2*d2; __syncthreads();
    for (int off=64; off>0; off>>=1){ if (c<off) red[c]+=red[c+off]; __syncthreads(); }
    float rs = rsqrtf(red[0]/384.f + 1e-5f);
    __syncthreads();
    xh[c]     = d0*rs*ln_s_scale[c];
    xh[c+128] = d1*rs*ln_s_scale[c+128];
    xh[c+256] = d2*rs*ln_s_scale[c+256];
    __syncthreads();
    float acc=0.f;
    for (int i=0;i<384;i++) acc += xh[i]*w_ts[i*CA_+c];
    ws_tsc[t*CA_+c]=acc;
}

// ---------------- kernel 3: queries_single_cond + row_act (S*Q blocks) -------
__global__ void k_queries(const float* ws_tok, const float* ws_tsc,
                          const int* a2q_idx, const int* a2q_mask,
                          const int* t2q_idx, const int* t2q_mask,
                          fp w_row,
                          float* ws_q, float* ws_rowa, float* out_q)
{
    int i = blockIdx.x; int c = threadIdx.x;
    __shared__ float r[128];
    __shared__ float part[128];
    float v = 0.f;
    if (a2q_mask[i]) v += ws_tok[a2q_idx[i]*CA_ + c];
    if (t2q_mask[i]) v += ws_tsc[t2q_idx[i]*CA_ + c];
    ws_q[i*CA_+c] = v;
    out_q[i*CA_+c] = v;
    r[c] = fmaxf(v, 0.f);
    __syncthreads();
    int j = c & 15, ch = c >> 4;
    float acc = 0.f;
    #pragma unroll
    for (int ii=0; ii<16; ii++) acc += r[ch*16+ii]*w_row[(ch*16+ii)*16+j];
    part[c] = acc; __syncthreads();
    if (c < 16){
        float a2 = 0.f;
        #pragma unroll
        for (int ch2=0; ch2<8; ch2++) a2 += part[ch2*16+c];
        ws_rowa[i*16+c] = a2;
    }
}

// ---------------- kernel 4: keys_single_cond + keys_mask + col_act (S*K) -----
__global__ void k_keys(const float* ws_q, const int* q2k_idx, const int* q2k_mask,
                       const int* queries_mask, fp w_col,
                       float* ws_cola, float* out_keys, float* out_kmask)
{
    int i = blockIdx.x; int c = threadIdx.x;
    __shared__ float r[128];
    __shared__ float part[128];
    int gi = q2k_idx[i]; int m = q2k_mask[i];
    float v = m ? ws_q[gi*CA_+c] : 0.f;
    out_keys[i*CA_+c] = v;
    if (c==0) out_kmask[i] = (m && queries_mask[gi]) ? 1.f : 0.f;
    r[c] = fmaxf(v, 0.f);
    __syncthreads();
    int j = c & 15, ch = c >> 4;
    float acc = 0.f;
    #pragma unroll
    for (int ii=0; ii<16; ii++) acc += r[ch*16+ii]*w_col[(ch*16+ii)*16+j];
    part[c] = acc; __syncthreads();
    if (c < 16){
        float a2 = 0.f;
        #pragma unroll
        for (int ch2=0; ch2<8; ch2++) a2 += part[ch2*16+c];
        ws_cola[i*16+c] = a2;
    }
}

// ---------------- kernel 5a: fold ln_p_scale into w_tp, compute col sums -----
__global__ void k_tpc_prep(fp w_tp, fp ln_p_scale)
{
    int i = threadIdx.x;  // 256
    for (int r = i; r < 2048; r += 256) g_wv[r] = w_tp[r] * ln_p_scale[r >> 4];
    __syncthreads();
    if (i < 16){
        float s = 0.f;
        #pragma unroll
        for (int c = 0; c < 128; c++) s += g_wv[c*16 + i];
        g_cw[i] = s;
    }
}

// ---------------- kernel 5b: tpc — one thread per row, line-clustered loads --
// tpc[pid][j] = rs * ( dot(x, wv[:,j]) - mu*cw[j] ),  mu/rs from raw x moments.
// R1 structure (no LDS, no barriers, wave-uniform weights -> s_load/K$), but
// the 512 B row is consumed as 4 x 128 B cache lines: the 8 dwordx4 loads of
// one line issue back-to-back and are consumed immediately (line lifetime ~8
// instrs instead of ~600), so L1 keeps the line across its 8 uses and the 3x
// HBM over-fetch disappears. #pragma unroll 1 keeps loads clustered per line.
__global__ __launch_bounds__(256) void k_tpc2(fp trunk_pair, float* ws_tpc)
{
    size_t pid = (size_t)blockIdx.x*256 + threadIdx.x;
    const float4* row = (const float4*)trunk_pair + pid*32;
    float pj[16];
    #pragma unroll
    for (int j=0;j<16;j++) pj[j]=0.f;
    float s1=0.f, s2=0.f;
    #pragma unroll 1
    for (int L=0; L<4; L++){
        float4 x0=row[L*8+0], x1=row[L*8+1], x2=row[L*8+2], x3=row[L*8+3];
        float4 x4=row[L*8+4], x5=row[L*8+5], x6=row[L*8+6], x7=row[L*8+7];
        const float* wb = g_wv + L*512;   // wave-uniform inductive base -> s_load
        s1 += (x0.x+x0.y)+(x0.z+x0.w) + (x1.x+x1.y)+(x1.z+x1.w)
            + (x2.x+x2.y)+(x2.z+x2.w) + (x3.x+x3.y)+(x3.z+x3.w)
            + (x4.x+x4.y)+(x4.z+x4.w) + (x5.x+x5.y)+(x5.z+x5.w)
            + (x6.x+x6.y)+(x6.z+x6.w) + (x7.x+x7.y)+(x7.z+x7.w);
        s2 += x0.x*x0.x+x0.y*x0.y+x0.z*x0.z+x0.w*x0.w
            + x1.x*x1.x+x1.y*x1.y+x1.z*x1.z+x1.w*x1.w
            + x2.x*x2.x+x2.y*x2.y+x2.z*x2.z+x2.w*x2.w
            + x3.x*x3.x+x3.y*x3.y+x3.z*x3.z+x3.w*x3.w
            + x4.x*x4.x+x4.y*x4.y+x4.z*x4.z+x4.w*x4.w
            + x5.x*x5.x+x5.y*x5.y+x5.z*x5.z+x5.w*x5.w
            + x6.x*x6.x+x6.y*x6.y+x6.z*x6.z+x6.w*x6.w
            + x7.x*x7.x+x7.y*x7.y+x7.z*x7.z+x7.w*x7.w;
        #pragma unroll
        for (int j=0;j<16;j++){
            float a;
            a  = x0.x*wb[0*64+j] + x0.y*wb[0*64+16+j] + x0.z*wb[0*64+32+j] + x0.w*wb[0*64+48+j];
            a += x1.x*wb[1*64+j] + x1.y*wb[1*64+16+j] + x1.z*wb[1*64+32+j] + x1.w*wb[1*64+48+j];
            a += x2.x*wb[2*64+j] + x2.y*wb[2*64+16+j] + x2.z*wb[2*64+32+j] + x2.w*wb[2*64+48+j];
            a += x3.x*wb[3*64+j] + x3.y*wb[3*64+16+j] + x3.z*wb[3*64+32+j] + x3.w*wb[3*64+48+j];
            a += x4.x*wb[4*64+j] + x4.y*wb[4*64+16+j] + x4.z*wb[4*64+32+j] + x4.w*wb[4*64+48+j];
            a += x5.x*wb[5*64+j] + x5.y*wb[5*64+16+j] + x5.z*wb[5*64+32+j] + x5.w*wb[5*64+48+j];
            a += x6.x*wb[6*64+j] + x6.y*wb[6*64+16+j] + x6.z*wb[6*64+32+j] + x6.w*wb[6*64+48+j];
            a += x7.x*wb[7*64+j] + x7.y*wb[7*64+16+j] + x7.z*wb[7*64+32+j] + x7.w*wb[7*64+48+j];
            pj[j] += a;
        }
    }
    float mu  = s1*(1.f/128.f);
    float var = s2*(1.f/128.f) - mu*mu;
    float rs  = rsqrtf(var + 1e-5f);
    float4* dst = (float4*)(ws_tpc + pid*16);
    #pragma unroll
    for (int j4=0;j4<4;j4++){
        float4 o;
        o.x = rs*(pj[j4*4+0] - mu*g_cw[j4*4+0]);
        o.y = rs*(pj[j4*4+1] - mu*g_cw[j4*4+1]);
        o.z = rs*(pj[j4*4+2] - mu*g_cw[j4*4+2]);
        o.w = rs*(pj[j4*4+3] - mu*g_cw[j4*4+3]);
        dst[j4]=o;
    }
}

// ---------------- kernel 6a/6b: geometry gathers -----------------------------
__global__ void k_qgeo(fp ref_ops, const int* ref_uid, const int* a2q_idx, const int* a2q_mask,
                       float* qpos, int* quid)
{
    int i = blockIdx.x*256 + threadIdx.x;
    if (i >= S_*Q_) return;
    int gi = a2q_idx[i]; int m = a2q_mask[i];
    qpos[i*3+0] = m ? ref_ops[gi*3+0] : 0.f;
    qpos[i*3+1] = m ? ref_ops[gi*3+1] : 0.f;
    qpos[i*3+2] = m ? ref_ops[gi*3+2] : 0.f;
    quid[i] = m ? ref_uid[gi] : 0;
}

__global__ void k_kgeo(const float* qpos, const int* ref_uid, const int* q2k_idx, const int* q2k_mask,
                       float* kpos, int* kuid)
{
    int i = blockIdx.x*256 + threadIdx.x;
    if (i >= S_*K_) return;
    int gi = q2k_idx[i]; int m = q2k_mask[i];
    kpos[i*3+0] = m ? qpos[gi*3+0] : 0.f;
    kpos[i*3+1] = m ? qpos[gi*3+1] : 0.f;
    kpos[i*3+2] = m ? qpos[gi*3+2] : 0.f;
    kuid[i] = m ? ref_uid[gi] : 0;   // NB: raw ref_space_uid flat, per reference
}

// ---------------- kernel 7: pair_act — 2 k-elems/thread, weights via s_load --
__global__ __launch_bounds__(256) void k_pair2(
    const float* ws_rowa, const float* ws_cola, const float* ws_tpc,
    const float* qpos, const float* kpos, const int* quid, const int* kuid,
    const int* t2q_idx, const int* t2q_mask, const int* t2k_idx, const int* t2k_mask,
    fp w_off, fp w_dist, fp w_valid, fp w_m1, fp w_m2, fp w_m3,
    float* out_pair)
{
    int tid = threadIdx.x;
    int sq  = blockIdx.x*4 + (tid>>6);      // wave-uniform
    int k0  = (tid&63)*2;
    int s   = sq >> 5;
    int sk0 = s*K_ + k0;

    float p0[16], p1[16];
    const float4* ra = (const float4*)(ws_rowa + (size_t)sq*16);
    const float4* ca = (const float4*)(ws_cola + (size_t)sk0*16);
    #pragma unroll
    for (int j4=0;j4<4;j4++){
        float4 a  = ra[j4];
        float4 b0 = ca[j4];
        float4 b1 = ca[4+j4];
        p0[j4*4+0]=a.x+b0.x; p0[j4*4+1]=a.y+b0.y; p0[j4*4+2]=a.z+b0.z; p0[j4*4+3]=a.w+b0.w;
        p1[j4*4+0]=a.x+b1.x; p1[j4*4+1]=a.y+b1.y; p1[j4*4+2]=a.z+b1.z; p1[j4*4+3]=a.w+b1.w;
    }

    int tqm = t2q_mask[sq];
    int tq  = t2q_idx[sq];
    int2 km = *(const int2*)(t2k_mask + sk0);
    int2 kv = *(const int2*)(t2k_idx + sk0);
    if (tqm && km.x){
        const float4* tp = (const float4*)(ws_tpc + (size_t)(tq*T_ + kv.x)*16);
        #pragma unroll
        for (int j4=0;j4<4;j4++){
            float4 v = tp[j4];
            p0[j4*4+0]+=v.x; p0[j4*4+1]+=v.y; p0[j4*4+2]+=v.z; p0[j4*4+3]+=v.w;
        }
    }
    if (tqm && km.y){
        const float4* tp = (const float4*)(ws_tpc + (size_t)(tq*T_ + kv.y)*16);
        #pragma unroll
        for (int j4=0;j4<4;j4++){
            float4 v = tp[j4];
            p1[j4*4+0]+=v.x; p1[j4*4+1]+=v.y; p1[j4*4+2]+=v.z; p1[j4*4+3]+=v.w;
        }
    }

    float qx=qpos[sq*3+0], qy=qpos[sq*3+1], qz=qpos[sq*3+2];
    int   qu=quid[sq];
    const float2* kp = (const float2*)(kpos + (size_t)sk0*3);  // 6 floats, 8B-aligned
    float2 ka=kp[0], kb=kp[1], kc=kp[2];
    int2 ku = *(const int2*)(kuid + sk0);
    {
        float ox=qx-ka.x, oy=qy-ka.y, oz=qz-kb.x;
        float val = (qu==ku.x) ? 1.f : 0.f;
        float invd = val/(1.f + ox*ox+oy*oy+oz*oz);
        ox*=val; oy*=val; oz*=val;
        #pragma unroll
        for (int j=0;j<16;j++)
            p0[j] += ox*w_off[j] + oy*w_off[16+j] + oz*w_off[32+j]
                   + invd*w_dist[j] + val*w_valid[j];
    }
    {
        float ox=qx-kb.y, oy=qy-kc.x, oz=qz-kc.y;
        float val = (qu==ku.y) ? 1.f : 0.f;
        float invd = val/(1.f + ox*ox+oy*oy+oz*oz);
        ox*=val; oy*=val; oz*=val;
        #pragma unroll
        for (int j=0;j<16;j++)
            p1[j] += ox*w_off[j] + oy*w_off[16+j] + oz*w_off[32+j]
                   + invd*w_dist[j] + val*w_valid[j];
    }

    // MLP: p += relu(relu(relu(p)@m1)@m2)@m3   (all static indexing)
    float h0[16], h1[16];
    #pragma unroll
    for (int j=0;j<16;j++){ h0[j]=0.f; h1[j]=0.f; }
    #pragma unroll
    for (int i=0;i<16;i++){
        float r0=fmaxf(p0[i],0.f), r1=fmaxf(p1[i],0.f);
        #pragma unroll
        for (int j=0;j<16;j++){ float w=w_m1[i*16+j]; h0[j]+=r0*w; h1[j]+=r1*w; }
    }
    float g0[16], g1[16];
    #pragma unroll
    for (int j=0;j<16;j++){ g0[j]=0.f; g1[j]=0.f; }
    #pragma unroll
    for (int i=0;i<16;i++){
        float r0=fmaxf(h0[i],0.f), r1=fmaxf(h1[i],0.f);
        #pragma unroll
        for (int j=0;j<16;j++){ float w=w_m2[i*16+j]; g0[j]+=r0*w; g1[j]+=r1*w; }
    }
    #pragma unroll
    for (int i=0;i<16;i++){
        float r0=fmaxf(g0[i],0.f), r1=fmaxf(g1[i],0.f);
        #pragma unroll
        for (int j=0;j<16;j++){ float w=w_m3[i*16+j]; p0[j]+=r0*w; p1[j]+=r1*w; }
    }

    float4* dst = (float4*)(out_pair + ((size_t)sq*K_ + k0)*16);
    #pragma unroll
    for (int j4=0;j4<4;j4++){
        float4 v0; v0.x=p0[j4*4+0]; v0.y=p0[j4*4+1]; v0.z=p0[j4*4+2]; v0.w=p0[j4*4+3];
        float4 v1; v1.x=p1[j4*4+0]; v1.y=p1[j4*4+1]; v1.z=p1[j4*4+2]; v1.w=p1[j4*4+3];
        dst[j4]   = v0;
        dst[4+j4] = v1;
    }
}

// ---------------- launch -----------------------------------------------------
extern "C" void kernel_launch(void* const* d_in, const int* in_sizes, int n_in,
                              void* d_out, int out_size, void* d_ws, size_t ws_size,
                              hipStream_t stream)
{
    fp trunk_single = (fp)d_in[0];
    fp trunk_pair   = (fp)d_in[1];
    fp ref_ops      = (fp)d_in[2];
    fp ref_mask     = (fp)d_in[3];
    const int* ref_element  = (const int*)d_in[4];
    fp ref_charge   = (fp)d_in[5];
    const int* name_chars   = (const int*)d_in[6];
    const int* ref_uid      = (const int*)d_in[7];
    const int* queries_mask = (const int*)d_in[8];
    const int* a2q_idx = (const int*)d_in[9];
    const int* a2q_mask= (const int*)d_in[10];
    const int* q2k_idx = (const int*)d_in[11];
    const int* q2k_mask= (const int*)d_in[12];
    const int* t2q_idx = (const int*)d_in[13];
    const int* t2q_mask= (const int*)d_in[14];
    const int* t2k_idx = (const int*)d_in[15];
    const int* t2k_mask= (const int*)d_in[16];
    fp w_pos  = (fp)d_in[17];
    fp w_maskw= (fp)d_in[18];
    fp w_elem = (fp)d_in[19];
    fp w_chg  = (fp)d_in[20];
    fp w_name = (fp)d_in[21];
    fp ln_s   = (fp)d_in[22];
    fp w_ts   = (fp)d_in[23];
    fp w_row  = (fp)d_in[24];
    fp w_col  = (fp)d_in[25];
    fp ln_p   = (fp)d_in[26];
    fp w_tp   = (fp)d_in[27];
    fp w_off  = (fp)d_in[28];
    fp w_dist = (fp)d_in[29];
    fp w_valid= (fp)d_in[30];
    fp w_m1   = (fp)d_in[31];
    fp w_m2   = (fp)d_in[32];
    fp w_m3   = (fp)d_in[33];

    float* out = (float*)d_out;
    float* out_q     = out;                                   // 2,359,296
    float* out_pair  = out + 2359296;                         // 37,748,736
    float* out_kmask = out + 2359296 + 37748736;              // 73,728
    float* out_keys  = out + 2359296 + 37748736 + 73728;      // 9,437,184

    float* ws = (float*)d_ws;                 // same layout as previous version
    float* ws_tok = ws;                       // T*A*CA    = 2,359,296
    float* ws_tsc = ws_tok + 2359296;         // T*CA      = 98,304
    float* ws_q   = ws_tsc + 98304;           // S*Q*CA    = 2,359,296
    float* ws_rowa= ws_q   + 2359296;         // S*Q*16    = 294,912
    float* ws_cola= ws_rowa+ 294912;          // S*K*16    = 1,179,648
    float* ws_tpc = ws_cola+ 1179648;         // T*T*16    = 9,437,184
    float* ws_qpos= ws_tpc + 9437184;         // S*Q*3     = 55,296
    float* ws_kpos= ws_qpos+ 55296;           // S*K*3     = 221,184
    int*   ws_quid= (int*)(ws_kpos + 221184); // S*Q       = 18,432
    int*   ws_kuid= ws_quid + 18432;          // S*K       = 73,728

    k_token_atoms<<<T_*A_, 128, 0, stream>>>(ref_ops, ref_mask, ref_element, ref_charge,
        name_chars, w_pos, w_maskw, w_elem, w_chg, w_name, ws_tok);
    k_tsc<<<T_, 128, 0, stream>>>(trunk_single, ln_s, w_ts, ws_tsc);
    k_queries<<<S_*Q_, 128, 0, stream>>>(ws_tok, ws_tsc, a2q_idx, a2q_mask, t2q_idx, t2q_mask,
        w_row, ws_q, ws_rowa, out_q);
    k_keys<<<S_*K_, 128, 0, stream>>>(ws_q, q2k_idx, q2k_mask, queries_mask, w_col,
        ws_cola, out_keys, out_kmask);
    k_tpc_prep<<<1, 256, 0, stream>>>(w_tp, ln_p);
    k_tpc2<<<(T_*T_)/256, 256, 0, stream>>>(trunk_pair, ws_tpc);
    k_qgeo<<<(S_*Q_+255)/256, 256, 0, stream>>>(ref_ops, ref_uid, a2q_idx, a2q_mask, ws_qpos, ws_quid);
    k_kgeo<<<(S_*K_+255)/256, 256, 0, stream>>>(ws_qpos, ref_uid, q2k_idx, q2k_mask, ws_kpos, ws_kuid);
    k_pair2<<<(S_*Q_*K_)/512, 256, 0, stream>>>(ws_rowa, ws_cola, ws_tpc, ws_qpos, ws_kpos,
        ws_quid, ws_kuid, t2q_idx, t2q_mask, t2k_idx, t2k_mask,
        w_off, w_dist, w_valid, w_m1, w_m2, w_m3, out_pair);
}

// Round 5
// 707.527 us; speedup vs baseline: 2.4284x; 1.1979x over previous
//
#include <hip/hip_runtime.h>

#define T_ 768
#define A_ 24
#define S_ 576
#define Q_ 32
#define K_ 128
#define CA_ 128
#define CP_ 16

typedef const float* fp;

// pre-scaled pair-LN weights: wv[c][j] = ln_p[c]*w_tp[c][j]; cw[j] = sum_c wv[c][j]
__device__ float g_wv[2048];
__device__ float g_cw[16];

// ---------------- kernel 1: token_atoms_single_cond (T*A blocks, 128 thr) ----
__global__ void k_token_atoms(fp ref_ops, fp ref_mask, const int* ref_element,
                              fp ref_charge, const int* name_chars,
                              fp w_pos, fp w_maskw, fp w_elem, fp w_chg, fp w_name,
                              float* ws_tok)
{
    int ta = blockIdx.x;
    int c  = threadIdx.x;
    float p0 = ref_ops[ta*3+0];
    float p1 = ref_ops[ta*3+1];
    float p2 = ref_ops[ta*3+2];
    float m  = ref_mask[ta];
    int   e  = ref_element[ta];
    float chg= asinhf(ref_charge[ta]);
    float acc = p0*w_pos[0*CA_+c] + p1*w_pos[1*CA_+c] + p2*w_pos[2*CA_+c];
    acc += m * w_maskw[c];
    acc += w_elem[e*CA_+c];
    acc += chg * w_chg[c];
    #pragma unroll
    for (int j=0;j<4;j++){
        int v = name_chars[ta*4+j];
        acc += w_name[(j*64+v)*CA_+c];
    }
    ws_tok[ta*CA_+c] = acc * m;
}

// ---------------- kernel 2: tsc = LN(trunk_single) @ w_ts (T blocks, 128 thr)
__global__ void k_tsc(fp trunk_single, fp ln_s_scale, fp w_ts, float* ws_tsc)
{
    int t = blockIdx.x; int c = threadIdx.x;
    __shared__ float xh[384];
    __shared__ float red[128];
    float x0 = trunk_single[t*384 + c];
    float x1 = trunk_single[t*384 + 128 + c];
    float x2 = trunk_single[t*384 + 256 + c];
    red[c] = x0+x1+x2; __syncthreads();
    for (int off=64; off>0; off>>=1){ if (c<off) red[c]+=red[c+off]; __syncthreads(); }
    float mu = red[0] / 384.f;
    __syncthreads();
    float d0=x0-mu, d1=x1-mu, d2=x2-mu;
    red[c] = d0*d0+d1*d1+d2*d2; __syncthreads();
    for (int off=64; off>0; off>>=1){ if (c<off) red[c]+=red[c+off]; __syncthreads(); }
    float rs = rsqrtf(red[0]/384.f + 1e-5f);
    __syncthreads();
    xh[c]     = d0*rs*ln_s_scale[c];
    xh[c+128] = d1*rs*ln_s_scale[c+128];
    xh[c+256] = d2*rs*ln_s_scale[c+256];
    __syncthreads();
    float acc=0.f;
    for (int i=0;i<384;i++) acc += xh[i]*w_ts[i*CA_+c];
    ws_tsc[t*CA_+c]=acc;
}

// ---------------- kernel 3: queries_single_cond + row_act (S*Q blocks) -------
__global__ void k_queries(const float* ws_tok, const float* ws_tsc,
                          const int* a2q_idx, const int* a2q_mask,
                          const int* t2q_idx, const int* t2q_mask,
                          fp w_row,
                          float* ws_q, float* ws_rowa, float* out_q)
{
    int i = blockIdx.x; int c = threadIdx.x;
    __shared__ float r[128];
    __shared__ float part[128];
    float v = 0.f;
    if (a2q_mask[i]) v += ws_tok[a2q_idx[i]*CA_ + c];
    if (t2q_mask[i]) v += ws_tsc[t2q_idx[i]*CA_ + c];
    ws_q[i*CA_+c] = v;
    out_q[i*CA_+c] = v;
    r[c] = fmaxf(v, 0.f);
    __syncthreads();
    int j = c & 15, ch = c >> 4;
    float acc = 0.f;
    #pragma unroll
    for (int ii=0; ii<16; ii++) acc += r[ch*16+ii]*w_row[(ch*16+ii)*16+j];
    part[c] = acc; __syncthreads();
    if (c < 16){
        float a2 = 0.f;
        #pragma unroll
        for (int ch2=0; ch2<8; ch2++) a2 += part[ch2*16+c];
        ws_rowa[i*16+c] = a2;
    }
}

// ---------------- kernel 4: keys_single_cond + keys_mask + col_act (S*K) -----
__global__ void k_keys(const float* ws_q, const int* q2k_idx, const int* q2k_mask,
                       const int* queries_mask, fp w_col,
                       float* ws_cola, float* out_keys, float* out_kmask)
{
    int i = blockIdx.x; int c = threadIdx.x;
    __shared__ float r[128];
    __shared__ float part[128];
    int gi = q2k_idx[i]; int m = q2k_mask[i];
    float v = m ? ws_q[gi*CA_+c] : 0.f;
    out_keys[i*CA_+c] = v;
    if (c==0) out_kmask[i] = (m && queries_mask[gi]) ? 1.f : 0.f;
    r[c] = fmaxf(v, 0.f);
    __syncthreads();
    int j = c & 15, ch = c >> 4;
    float acc = 0.f;
    #pragma unroll
    for (int ii=0; ii<16; ii++) acc += r[ch*16+ii]*w_col[(ch*16+ii)*16+j];
    part[c] = acc; __syncthreads();
    if (c < 16){
        float a2 = 0.f;
        #pragma unroll
        for (int ch2=0; ch2<8; ch2++) a2 += part[ch2*16+c];
        ws_cola[i*16+c] = a2;
    }
}

// ---------------- kernel 5a: fold ln_p_scale into w_tp, compute col sums -----
__global__ void k_tpc_prep(fp w_tp, fp ln_p_scale)
{
    int i = threadIdx.x;  // 256
    for (int r = i; r < 2048; r += 256) g_wv[r] = w_tp[r] * ln_p_scale[r >> 4];
    __syncthreads();
    if (i < 16){
        float s = 0.f;
        #pragma unroll
        for (int c = 0; c < 128; c++) s += g_wv[c*16 + i];
        g_cw[i] = s;
    }
}

// ---------------- kernel 5b: tpc v3 — LDS-tiled, weights-per-lane GEMM -------
// tpc[row][j] = rs * ( dot(x, wv[:,j]) - mu*cw[j] ).
// Block=256thr, tile=64 rows. Stage X coalesced to LDS (pitch 132 floats so the
// 4 rg-addresses per ds_read land 16 banks apart -> free 2-way conflict).
// Lane = (j = t&15, rg = t>>4): holds weight column wv[:,j] in 128 VGPRs
// (loaded once per block), computes rows rg*4..+3 from LDS. No SMEM weight
// stream, no per-lane scattered global reads. All indices compile-time.
#define TPC_ROWS 64
#define TPC_PITCH 132
__global__ __launch_bounds__(256, 2) void k_tpc3(fp trunk_pair, float* ws_tpc)
{
    __shared__ float xs[TPC_ROWS * TPC_PITCH];   // 33,792 B
    __shared__ float p1s[256], p2s[256];
    __shared__ float mus[TPC_ROWS], rss[TPC_ROWS];

    int t  = threadIdx.x;
    int j  = t & 15;
    int rg = t >> 4;

    float wj[128];
    #pragma unroll
    for (int c = 0; c < 128; c++) wj[c] = g_wv[c*16 + j];
    float cwj = g_cw[j];

    #pragma unroll 1
    for (int it = 0; it < 4; it++){
        int tile = blockIdx.x*4 + it;
        const float4* src = (const float4*)trunk_pair + (size_t)tile * (TPC_ROWS*32);

        __syncthreads();                      // previous tile fully consumed
        #pragma unroll
        for (int p = 0; p < 8; p++){          // coalesced stage: 2048 f4 / 256 thr
            int li = p*256 + t;
            int r = li >> 5, c4 = li & 31;
            float4 v = src[li];
            *(float4*)(xs + r*TPC_PITCH + c4*4) = v;
        }
        __syncthreads();
        {                                     // moments: 4 threads per row
            int rm = t >> 2, mq = t & 3;
            const float* xr = xs + rm*TPC_PITCH + mq*32;
            float s1 = 0.f, s2 = 0.f;
            #pragma unroll
            for (int i = 0; i < 8; i++){
                float4 v = *(const float4*)(xr + i*4);
                s1 += (v.x+v.y)+(v.z+v.w);
                s2 += v.x*v.x+v.y*v.y+v.z*v.z+v.w*v.w;
            }
            p1s[t] = s1; p2s[t] = s2;
        }
        __syncthreads();
        if (t < TPC_ROWS){
            float s1 = p1s[t*4]+p1s[t*4+1]+p1s[t*4+2]+p1s[t*4+3];
            float s2 = p2s[t*4]+p2s[t*4+1]+p2s[t*4+2]+p2s[t*4+3];
            float mu = s1*(1.f/128.f);
            float var = s2*(1.f/128.f) - mu*mu;
            mus[t] = mu; rss[t] = rsqrtf(var + 1e-5f);
        }
        __syncthreads();
        float pj0=0.f, pj1=0.f, pj2=0.f, pj3=0.f;
        const float* x0 = xs + (rg*4+0)*TPC_PITCH;
        const float* x1 = xs + (rg*4+1)*TPC_PITCH;
        const float* x2 = xs + (rg*4+2)*TPC_PITCH;
        const float* x3 = xs + (rg*4+3)*TPC_PITCH;
        #pragma unroll
        for (int c4 = 0; c4 < 32; c4++){
            float4 a = *(const float4*)(x0 + c4*4);
            float4 b = *(const float4*)(x1 + c4*4);
            float4 c = *(const float4*)(x2 + c4*4);
            float4 d = *(const float4*)(x3 + c4*4);
            float w0 = wj[c4*4+0], w1 = wj[c4*4+1], w2 = wj[c4*4+2], w3 = wj[c4*4+3];
            pj0 += a.x*w0 + a.y*w1 + a.z*w2 + a.w*w3;
            pj1 += b.x*w0 + b.y*w1 + b.z*w2 + b.w*w3;
            pj2 += c.x*w0 + c.y*w1 + c.z*w2 + c.w*w3;
            pj3 += d.x*w0 + d.y*w1 + d.z*w2 + d.w*w3;
        }
        size_t rowbase = (size_t)tile*TPC_ROWS + rg*4;
        float* dst = ws_tpc + rowbase*16 + j;
        dst[0]  = rss[rg*4+0]*(pj0 - mus[rg*4+0]*cwj);
        dst[16] = rss[rg*4+1]*(pj1 - mus[rg*4+1]*cwj);
        dst[32] = rss[rg*4+2]*(pj2 - mus[rg*4+2]*cwj);
        dst[48] = rss[rg*4+3]*(pj3 - mus[rg*4+3]*cwj);
    }
}

// ---------------- kernel 6a/6b: geometry gathers -----------------------------
__global__ void k_qgeo(fp ref_ops, const int* ref_uid, const int* a2q_idx, const int* a2q_mask,
                       float* qpos, int* quid)
{
    int i = blockIdx.x*256 + threadIdx.x;
    if (i >= S_*Q_) return;
    int gi = a2q_idx[i]; int m = a2q_mask[i];
    qpos[i*3+0] = m ? ref_ops[gi*3+0] : 0.f;
    qpos[i*3+1] = m ? ref_ops[gi*3+1] : 0.f;
    qpos[i*3+2] = m ? ref_ops[gi*3+2] : 0.f;
    quid[i] = m ? ref_uid[gi] : 0;
}

__global__ void k_kgeo(const float* qpos, const int* ref_uid, const int* q2k_idx, const int* q2k_mask,
                       float* kpos, int* kuid)
{
    int i = blockIdx.x*256 + threadIdx.x;
    if (i >= S_*K_) return;
    int gi = q2k_idx[i]; int m = q2k_mask[i];
    kpos[i*3+0] = m ? qpos[gi*3+0] : 0.f;
    kpos[i*3+1] = m ? qpos[gi*3+1] : 0.f;
    kpos[i*3+2] = m ? qpos[gi*3+2] : 0.f;
    kuid[i] = m ? ref_uid[gi] : 0;   // NB: raw ref_space_uid flat, per reference
}

// ---------------- kernel 7: pair_act — 2 k-elems/thread, weights via s_load --
__global__ __launch_bounds__(256) void k_pair2(
    const float* ws_rowa, const float* ws_cola, const float* ws_tpc,
    const float* qpos, const float* kpos, const int* quid, const int* kuid,
    const int* t2q_idx, const int* t2q_mask, const int* t2k_idx, const int* t2k_mask,
    fp w_off, fp w_dist, fp w_valid, fp w_m1, fp w_m2, fp w_m3,
    float* out_pair)
{
    int tid = threadIdx.x;
    int sq  = blockIdx.x*4 + (tid>>6);      // wave-uniform
    int k0  = (tid&63)*2;
    int s   = sq >> 5;
    int sk0 = s*K_ + k0;

    float p0[16], p1[16];
    const float4* ra = (const float4*)(ws_rowa + (size_t)sq*16);
    const float4* ca = (const float4*)(ws_cola + (size_t)sk0*16);
    #pragma unroll
    for (int j4=0;j4<4;j4++){
        float4 a  = ra[j4];
        float4 b0 = ca[j4];
        float4 b1 = ca[4+j4];
        p0[j4*4+0]=a.x+b0.x; p0[j4*4+1]=a.y+b0.y; p0[j4*4+2]=a.z+b0.z; p0[j4*4+3]=a.w+b0.w;
        p1[j4*4+0]=a.x+b1.x; p1[j4*4+1]=a.y+b1.y; p1[j4*4+2]=a.z+b1.z; p1[j4*4+3]=a.w+b1.w;
    }

    int tqm = t2q_mask[sq];
    int tq  = t2q_idx[sq];
    int2 km = *(const int2*)(t2k_mask + sk0);
    int2 kv = *(const int2*)(t2k_idx + sk0);
    if (tqm && km.x){
        const float4* tp = (const float4*)(ws_tpc + (size_t)(tq*T_ + kv.x)*16);
        #pragma unroll
        for (int j4=0;j4<4;j4++){
            float4 v = tp[j4];
            p0[j4*4+0]+=v.x; p0[j4*4+1]+=v.y; p0[j4*4+2]+=v.z; p0[j4*4+3]+=v.w;
        }
    }
    if (tqm && km.y){
        const float4* tp = (const float4*)(ws_tpc + (size_t)(tq*T_ + kv.y)*16);
        #pragma unroll
        for (int j4=0;j4<4;j4++){
            float4 v = tp[j4];
            p1[j4*4+0]+=v.x; p1[j4*4+1]+=v.y; p1[j4*4+2]+=v.z; p1[j4*4+3]+=v.w;
        }
    }

    float qx=qpos[sq*3+0], qy=qpos[sq*3+1], qz=qpos[sq*3+2];
    int   qu=quid[sq];
    const float2* kp = (const float2*)(kpos + (size_t)sk0*3);  // 6 floats, 8B-aligned
    float2 ka=kp[0], kb=kp[1], kc=kp[2];
    int2 ku = *(const int2*)(kuid + sk0);
    {
        float ox=qx-ka.x, oy=qy-ka.y, oz=qz-kb.x;
        float val = (qu==ku.x) ? 1.f : 0.f;
        float invd = val/(1.f + ox*ox+oy*oy+oz*oz);
        ox*=val; oy*=val; oz*=val;
        #pragma unroll
        for (int j=0;j<16;j++)
            p0[j] += ox*w_off[j] + oy*w_off[16+j] + oz*w_off[32+j]
                   + invd*w_dist[j] + val*w_valid[j];
    }
    {
        float ox=qx-kb.y, oy=qy-kc.x, oz=qz-kc.y;
        float val = (qu==ku.y) ? 1.f : 0.f;
        float invd = val/(1.f + ox*ox+oy*oy+oz*oz);
        ox*=val; oy*=val; oz*=val;
        #pragma unroll
        for (int j=0;j<16;j++)
            p1[j] += ox*w_off[j] + oy*w_off[16+j] + oz*w_off[32+j]
                   + invd*w_dist[j] + val*w_valid[j];
    }

    // MLP: p += relu(relu(relu(p)@m1)@m2)@m3   (all static indexing)
    float h0[16], h1[16];
    #pragma unroll
    for (int j=0;j<16;j++){ h0[j]=0.f; h1[j]=0.f; }
    #pragma unroll
    for (int i=0;i<16;i++){
        float r0=fmaxf(p0[i],0.f), r1=fmaxf(p1[i],0.f);
        #pragma unroll
        for (int j=0;j<16;j++){ float w=w_m1[i*16+j]; h0[j]+=r0*w; h1[j]+=r1*w; }
    }
    float g0[16], g1[16];
    #pragma unroll
    for (int j=0;j<16;j++){ g0[j]=0.f; g1[j]=0.f; }
    #pragma unroll
    for (int i=0;i<16;i++){
        float r0=fmaxf(h0[i],0.f), r1=fmaxf(h1[i],0.f);
        #pragma unroll
        for (int j=0;j<16;j++){ float w=w_m2[i*16+j]; g0[j]+=r0*w; g1[j]+=r1*w; }
    }
    #pragma unroll
    for (int i=0;i<16;i++){
        float r0=fmaxf(g0[i],0.f), r1=fmaxf(g1[i],0.f);
        #pragma unroll
        for (int j=0;j<16;j++){ float w=w_m3[i*16+j]; p0[j]+=r0*w; p1[j]+=r1*w; }
    }

    float4* dst = (float4*)(out_pair + ((size_t)sq*K_ + k0)*16);
    #pragma unroll
    for (int j4=0;j4<4;j4++){
        float4 v0; v0.x=p0[j4*4+0]; v0.y=p0[j4*4+1]; v0.z=p0[j4*4+2]; v0.w=p0[j4*4+3];
        float4 v1; v1.x=p1[j4*4+0]; v1.y=p1[j4*4+1]; v1.z=p1[j4*4+2]; v1.w=p1[j4*4+3];
        dst[j4]   = v0;
        dst[4+j4] = v1;
    }
}

// ---------------- launch -----------------------------------------------------
extern "C" void kernel_launch(void* const* d_in, const int* in_sizes, int n_in,
                              void* d_out, int out_size, void* d_ws, size_t ws_size,
                              hipStream_t stream)
{
    fp trunk_single = (fp)d_in[0];
    fp trunk_pair   = (fp)d_in[1];
    fp ref_ops      = (fp)d_in[2];
    fp ref_mask     = (fp)d_in[3];
    const int* ref_element  = (const int*)d_in[4];
    fp ref_charge   = (fp)d_in[5];
    const int* name_chars   = (const int*)d_in[6];
    const int* ref_uid      = (const int*)d_in[7];
    const int* queries_mask = (const int*)d_in[8];
    const int* a2q_idx = (const int*)d_in[9];
    const int* a2q_mask= (const int*)d_in[10];
    const int* q2k_idx = (const int*)d_in[11];
    const int* q2k_mask= (const int*)d_in[12];
    const int* t2q_idx = (const int*)d_in[13];
    const int* t2q_mask= (const int*)d_in[14];
    const int* t2k_idx = (const int*)d_in[15];
    const int* t2k_mask= (const int*)d_in[16];
    fp w_pos  = (fp)d_in[17];
    fp w_maskw= (fp)d_in[18];
    fp w_elem = (fp)d_in[19];
    fp w_chg  = (fp)d_in[20];
    fp w_name = (fp)d_in[21];
    fp ln_s   = (fp)d_in[22];
    fp w_ts   = (fp)d_in[23];
    fp w_row  = (fp)d_in[24];
    fp w_col  = (fp)d_in[25];
    fp ln_p   = (fp)d_in[26];
    fp w_tp   = (fp)d_in[27];
    fp w_off  = (fp)d_in[28];
    fp w_dist = (fp)d_in[29];
    fp w_valid= (fp)d_in[30];
    fp w_m1   = (fp)d_in[31];
    fp w_m2   = (fp)d_in[32];
    fp w_m3   = (fp)d_in[33];

    float* out = (float*)d_out;
    float* out_q     = out;                                   // 2,359,296
    float* out_pair  = out + 2359296;                         // 37,748,736
    float* out_kmask = out + 2359296 + 37748736;              // 73,728
    float* out_keys  = out + 2359296 + 37748736 + 73728;      // 9,437,184

    float* ws = (float*)d_ws;                 // same layout as previous version
    float* ws_tok = ws;                       // T*A*CA    = 2,359,296
    float* ws_tsc = ws_tok + 2359296;         // T*CA      = 98,304
    float* ws_q   = ws_tsc + 98304;           // S*Q*CA    = 2,359,296
    float* ws_rowa= ws_q   + 2359296;         // S*Q*16    = 294,912
    float* ws_cola= ws_rowa+ 294912;          // S*K*16    = 1,179,648
    float* ws_tpc = ws_cola+ 1179648;         // T*T*16    = 9,437,184
    float* ws_qpos= ws_tpc + 9437184;         // S*Q*3     = 55,296
    float* ws_kpos= ws_qpos+ 55296;           // S*K*3     = 221,184
    int*   ws_quid= (int*)(ws_kpos + 221184); // S*Q       = 18,432
    int*   ws_kuid= ws_quid + 18432;          // S*K       = 73,728

    k_token_atoms<<<T_*A_, 128, 0, stream>>>(ref_ops, ref_mask, ref_element, ref_charge,
        name_chars, w_pos, w_maskw, w_elem, w_chg, w_name, ws_tok);
    k_tsc<<<T_, 128, 0, stream>>>(trunk_single, ln_s, w_ts, ws_tsc);
    k_queries<<<S_*Q_, 128, 0, stream>>>(ws_tok, ws_tsc, a2q_idx, a2q_mask, t2q_idx, t2q_mask,
        w_row, ws_q, ws_rowa, out_q);
    k_keys<<<S_*K_, 128, 0, stream>>>(ws_q, q2k_idx, q2k_mask, queries_mask, w_col,
        ws_cola, out_keys, out_kmask);
    k_tpc_prep<<<1, 256, 0, stream>>>(w_tp, ln_p);
    k_tpc3<<<(T_*T_)/(TPC_ROWS*4), 256, 0, stream>>>(trunk_pair, ws_tpc);
    k_qgeo<<<(S_*Q_+255)/256, 256, 0, stream>>>(ref_ops, ref_uid, a2q_idx, a2q_mask, ws_qpos, ws_quid);
    k_kgeo<<<(S_*K_+255)/256, 256, 0, stream>>>(ws_qpos, ref_uid, q2k_idx, q2k_mask, ws_kpos, ws_kuid);
    k_pair2<<<(S_*Q_*K_)/512, 256, 0, stream>>>(ws_rowa, ws_cola, ws_tpc, ws_qpos, ws_kpos,
        ws_quid, ws_kuid, t2q_idx, t2q_mask, t2k_idx, t2k_mask,
        w_off, w_dist, w_valid, w_m1, w_m2, w_m3, out_pair);
}